// Round 5
// baseline (1262.470 us; speedup 1.0000x reference)
//
#include <hip/hip_runtime.h>
#include <hip/hip_bf16.h>

#define NHEADS 3
#define SSH 4
#define NWD 32            // windows per dim
#define PXI 65536         // pixels per image plane
#define SCALE 0.17677669529663687f

// ---------------------------------------------------------------------------
// K1: QKV 1x1 conv for image b (GEMM 288x96 @ 96x65536),
// writes windowed qkv_b [1024][64][288] + V in per-b NCHW [96][PXI]. fp32.
// grid (1024 px-tiles, 3 oc-tiles), block 256
// ---------------------------------------------------------------------------
__global__ __launch_bounds__(256) void k1_qkv(
    const float* __restrict__ x, const float* __restrict__ Wqk,
    const float* __restrict__ bqk, const float* __restrict__ Wv,
    const float* __restrict__ bv, float* __restrict__ qkv_b,
    float* __restrict__ v_b, int b) {
  __shared__ float Wt[96 * 97];   // [c][oc_l] padded
  __shared__ float Xt[96 * 64];   // [c][px]
  const int tid = threadIdx.x;
  const int pt = blockIdx.x, ot = blockIdx.y;
  const int oc0 = ot * 96;
  const int p0 = pt * 64;

  for (int i = tid; i < 96 * 96; i += 256) {
    int c = i % 96, oc_l = i / 96;
    int oc = oc0 + oc_l;
    float w = (oc < 192) ? Wqk[oc * 96 + c] : Wv[(oc - 192) * 96 + c];
    Wt[c * 97 + oc_l] = w;
  }
  for (int i = tid; i < 96 * 64; i += 256) {
    int c = i >> 6, px = i & 63;
    Xt[i] = x[(size_t)(b * 96 + c) * PXI + p0 + px];
  }
  __syncthreads();

  const int tx = tid & 15, ty = tid >> 4;
  float acc[6][4];
#pragma unroll
  for (int r = 0; r < 6; r++)
#pragma unroll
    for (int s = 0; s < 4; s++) acc[r][s] = 0.f;

#pragma unroll 8
  for (int c = 0; c < 96; c++) {
    float xa[4];
#pragma unroll
    for (int s = 0; s < 4; s++) xa[s] = Xt[c * 64 + tx + 16 * s];
#pragma unroll
    for (int r = 0; r < 6; r++) {
      float wv = Wt[c * 97 + ty + 16 * r];
#pragma unroll
      for (int s = 0; s < 4; s++) acc[r][s] += wv * xa[s];
    }
  }

#pragma unroll
  for (int r = 0; r < 6; r++) {
    int oc = oc0 + ty + 16 * r;
    float bb = (oc < 192) ? bqk[oc] : bv[oc - 192];
#pragma unroll
    for (int s = 0; s < 4; s++) {
      int p = p0 + tx + 16 * s;
      float val = acc[r][s] + bb;
      int h = p >> 8, w = p & 255;
      int hp = (h + 252) & 255, wp = (w + 252) & 255;  // rolled coords
      int wh = hp >> 3, ii = hp & 7, ww = wp >> 3, jj = wp & 7;
      int win = wh * NWD + ww;
      int n = ii * 8 + jj;
      qkv_b[(size_t)(win * 64 + n) * 288 + oc] = val;
      if (oc >= 192) v_b[(size_t)(oc - 192) * PXI + p] = val;
    }
  }
}

// ---------------------------------------------------------------------------
// K2: relative-position bias MLP -> bias_ws[head][n][m]  (fp32)
// ---------------------------------------------------------------------------
__global__ __launch_bounds__(256) void k2_bias(
    const float* __restrict__ Wm1, const float* __restrict__ bm1,
    const float* __restrict__ Wm2, const float* __restrict__ bm2,
    float* __restrict__ bias_ws) {
  int pair = blockIdx.x * 256 + threadIdx.x;  // 0..4095
  int n = pair >> 6, m = pair & 63;
  float d0 = (float)((n >> 3) - (m >> 3));
  float d1 = (float)((n & 7) - (m & 7));
  float r0 = (d0 > 0.f ? 1.f : (d0 < 0.f ? -1.f : 0.f)) * log1pf(fabsf(d0));
  float r1 = (d1 > 0.f ? 1.f : (d1 < 0.f ? -1.f : 0.f)) * log1pf(fabsf(d1));
  float a0 = 0.f, a1 = 0.f, a2 = 0.f;
  for (int j = 0; j < 256; j++) {
    float hb = r0 * Wm1[j] + r1 * Wm1[256 + j] + bm1[j];
    hb = fmaxf(hb, 0.f);
    a0 += hb * Wm2[j * 3 + 0];
    a1 += hb * Wm2[j * 3 + 1];
    a2 += hb * Wm2[j * 3 + 2];
  }
  bias_ws[0 * 4096 + pair] = a0 + bm2[0];
  bias_ws[1 * 4096 + pair] = a1 + bm2[1];
  bias_ws[2 * 4096 + pair] = a2 + bm2[2];
}

// ---------------------------------------------------------------------------
// K3: windowed attention for image b. grid 1024 (one block per window). fp32.
// ---------------------------------------------------------------------------
__global__ __launch_bounds__(256) void k3_attn(
    const float* __restrict__ qkv_b, const float* __restrict__ bias_ws,
    float* __restrict__ o_b) {
  __shared__ float Q[64 * 33], K[64 * 33], V[64 * 33];
  __shared__ float S[64 * 65];
  const int tid = threadIdx.x;
  const int b_ = blockIdx.x;          // window index 0..1023
  const int wh = b_ >> 5, ww = b_ & 31;

  for (int hd = 0; hd < NHEADS; hd++) {
    for (int i = tid; i < 64 * 32; i += 256) {
      int n = i >> 5, d = i & 31;
      size_t base = (size_t)(b_ * 64 + n) * 288 + hd * 32 + d;
      Q[n * 33 + d] = qkv_b[base];
      K[n * 33 + d] = qkv_b[base + 96];
      V[n * 33 + d] = qkv_b[base + 192];
    }
    __syncthreads();

    {
      int n = tid >> 2, mg = tid & 3;
      int in_ = n >> 3, jn = n & 7;
      int rn = ((wh == 31) ? (in_ < 4 ? 1 : 2) : 0) * 3 +
               ((ww == 31) ? (jn < 4 ? 1 : 2) : 0);
#pragma unroll 4
      for (int mi = 0; mi < 16; mi++) {
        int m = mg * 16 + mi;
        float sum = 0.f;
#pragma unroll
        for (int k = 0; k < 32; k++) sum += Q[n * 33 + k] * K[m * 33 + k];
        int im = m >> 3, jm = m & 7;
        int rm = ((wh == 31) ? (im < 4 ? 1 : 2) : 0) * 3 +
                 ((ww == 31) ? (jm < 4 ? 1 : 2) : 0);
        float msk = (rm != rn) ? -100.f : 0.f;
        S[n * 65 + m] = sum * SCALE + bias_ws[hd * 4096 + n * 64 + m] + msk;
      }
    }
    __syncthreads();

    if (tid < 64) {
      float mx = -1e30f;
      for (int m = 0; m < 64; m++) mx = fmaxf(mx, S[tid * 65 + m]);
      float sm = 0.f;
      for (int m = 0; m < 64; m++) {
        float e = __expf(S[tid * 65 + m] - mx);
        S[tid * 65 + m] = e;
        sm += e;
      }
      float inv = 1.f / sm;
      for (int m = 0; m < 64; m++) S[tid * 65 + m] *= inv;
    }
    __syncthreads();

    {
      int n = tid >> 2, dg = tid & 3;
      float o[8];
#pragma unroll
      for (int d = 0; d < 8; d++) o[d] = 0.f;
      for (int m = 0; m < 64; m++) {
        float s = S[n * 65 + m];
        const float* vv = &V[m * 33 + dg * 8];
#pragma unroll
        for (int d = 0; d < 8; d++) o[d] += s * vv[d];
      }
      int ii = n >> 3, jj = n & 7;
      int hpix = ((wh << 3) + ii + SSH) & 255;
      int wpix = ((ww << 3) + jj + SSH) & 255;
      int pix = (hpix << 8) + wpix;
#pragma unroll
      for (int d = 0; d < 8; d++) {
        int cch = hd * 32 + dg * 8 + d;
        o_b[(size_t)cch * PXI + pix] = o[d];
      }
    }
    __syncthreads();
  }
}

// ---------------------------------------------------------------------------
// K4: depthwise 5x5 (reflect pad) + bdw + O -> t_b, per image. grid 24576.
// ---------------------------------------------------------------------------
__global__ __launch_bounds__(256) void k4_dw(
    const float* __restrict__ v_b, const float* __restrict__ o_b,
    const float* __restrict__ Wdw, const float* __restrict__ bdw,
    float* __restrict__ t_b) {
  const int blk = blockIdx.x;      // 0..24575
  const int c = blk >> 8;
  const int h = blk & 255;
  const int w = threadIdx.x;
  __shared__ float wd[25];
  __shared__ float bd;
  if (threadIdx.x < 25) wd[threadIdx.x] = Wdw[c * 25 + threadIdx.x];
  if (threadIdx.x == 32) bd = bdw[c];
  __syncthreads();

  const float* vp = v_b + ((size_t)c << 16);
  float acc = bd;
#pragma unroll
  for (int dy = 0; dy < 5; dy++) {
    int hh = h + dy - 2;
    hh = hh < 0 ? -hh : (hh > 255 ? 510 - hh : hh);
    const float* row = vp + (hh << 8);
#pragma unroll
    for (int dx = 0; dx < 5; dx++) {
      int wx = w + dx - 2;
      wx = wx < 0 ? -wx : (wx > 255 ? 510 - wx : wx);
      acc += row[wx] * wd[dy * 5 + dx];
    }
  }
  size_t idx = ((size_t)c << 16) + (h << 8) + w;
  acc += o_b[idx];
  t_b[idx] = acc;
}

// ---------------------------------------------------------------------------
// K5: projection GEMM 96x96 for image b -> d_out (fp32 NCHW). grid 1024.
// ---------------------------------------------------------------------------
__global__ __launch_bounds__(256) void k5_proj(
    const float* __restrict__ t_b, const float* __restrict__ Wp,
    const float* __restrict__ bp, float* __restrict__ out, int b) {
  __shared__ float Wt[96 * 97];
  __shared__ float Xt[96 * 64];
  const int tid = threadIdx.x;
  const int pt = blockIdx.x;
  const int p0 = pt * 64;

  for (int i = tid; i < 96 * 96; i += 256) {
    int c = i % 96, oc_l = i / 96;
    Wt[c * 97 + oc_l] = Wp[oc_l * 96 + c];
  }
  for (int i = tid; i < 96 * 64; i += 256) {
    int c = i >> 6, px = i & 63;
    Xt[i] = t_b[(size_t)c * PXI + p0 + px];
  }
  __syncthreads();

  const int tx = tid & 15, ty = tid >> 4;
  float acc[6][4];
#pragma unroll
  for (int r = 0; r < 6; r++)
#pragma unroll
    for (int s = 0; s < 4; s++) acc[r][s] = 0.f;

#pragma unroll 8
  for (int c = 0; c < 96; c++) {
    float xa[4];
#pragma unroll
    for (int s = 0; s < 4; s++) xa[s] = Xt[c * 64 + tx + 16 * s];
#pragma unroll
    for (int r = 0; r < 6; r++) {
      float wv = Wt[c * 97 + ty + 16 * r];
#pragma unroll
      for (int s = 0; s < 4; s++) acc[r][s] += wv * xa[s];
    }
  }

#pragma unroll
  for (int r = 0; r < 6; r++) {
    int oc = ty + 16 * r;
    float bb = bp[oc];
#pragma unroll
    for (int s = 0; s < 4; s++) {
      int p = p0 + tx + 16 * s;
      out[(size_t)(b * 96 + oc) * PXI + p] = acc[r][s] + bb;
    }
  }
}

// ---------------------------------------------------------------------------
extern "C" void kernel_launch(void* const* d_in, const int* in_sizes, int n_in,
                              void* d_out, int out_size, void* d_ws,
                              size_t ws_size, hipStream_t stream) {
  const float* x   = (const float*)d_in[0];
  const float* Wv  = (const float*)d_in[1];
  const float* bv  = (const float*)d_in[2];
  const float* Wqk = (const float*)d_in[3];
  const float* bqk = (const float*)d_in[4];
  const float* Wm1 = (const float*)d_in[5];
  const float* bm1 = (const float*)d_in[6];
  const float* Wm2 = (const float*)d_in[7];
  const float* bm2 = (const float*)d_in[8];
  const float* Wdw = (const float*)d_in[9];
  const float* bdw = (const float*)d_in[10];
  const float* Wp  = (const float*)d_in[11];
  const float* bp  = (const float*)d_in[12];

  // per-image fp32 workspace (reused across b), total ~120 MiB
  // (R4 proved >= 227.5 MB writable):
  //   [0, 75497472)            qkv_b  fp32 [1024][64][288] (t_b aliases)
  //   [75497472, 100663296)    v_b    fp32 [96][65536]
  //   [100663296, 125829120)   o_b    fp32 [96][65536]
  //   [125829120, 125878272)   bias_ws fp32 [3][64][64]
  char* ws = (char*)d_ws;
  float* qkv_b = (float*)ws;
  float* t_b   = (float*)ws;
  float* v_b   = (float*)(ws + 75497472);
  float* o_b   = (float*)(ws + 100663296);
  float* bias_ws = (float*)(ws + 125829120);

  k2_bias<<<16, 256, 0, stream>>>(Wm1, bm1, Wm2, bm2, bias_ws);
  for (int b = 0; b < 4; b++) {
    k1_qkv<<<dim3(1024, 3), 256, 0, stream>>>(x, Wqk, bqk, Wv, bv, qkv_b, v_b, b);
    k3_attn<<<1024, 256, 0, stream>>>(qkv_b, bias_ws, o_b);
    k4_dw<<<24576, 256, 0, stream>>>(v_b, o_b, Wdw, bdw, t_b);
    k5_proj<<<1024, 256, 0, stream>>>(t_b, Wp, bp, (float*)d_out, b);
  }
}